// Round 1
// baseline (190.610 us; speedup 1.0000x reference)
//
#include <hip/hip_runtime.h>
#include <math.h>

#define N_NODES 50000
#define N_EDGES 800000
#define D_FEAT 64

// Kernel 1: row_ptr[r] = lower_bound(rows, r) for r in [0, N_NODES]
__global__ __launch_bounds__(256) void build_row_ptr(const int* __restrict__ rows,
                                                     int* __restrict__ row_ptr) {
    int r = blockIdx.x * blockDim.x + threadIdx.x;
    if (r > N_NODES) return;
    int lo = 0, hi = N_EDGES;
    while (lo < hi) {
        int mid = (lo + hi) >> 1;
        if (rows[mid] < r) lo = mid + 1; else hi = mid;
    }
    row_ptr[r] = lo;
}

// Kernel 2: one wave per row, one lane per feature.
// y[row][lane] = elu(scalar * sum_e vals[e] * h_in[cols[e]][lane])
// If FUSE: additionally out[row][j] = b[j] + sum_d y[row][d] * W[j][d]
template <bool FUSE>
__global__ __launch_bounds__(256) void gcn_layer(
    const float* __restrict__ h_in,      // [N_NODES, 64]
    const int*   __restrict__ cols,      // [N_EDGES]
    const float* __restrict__ vals,      // [N_EDGES]
    const int*   __restrict__ row_ptr,   // [N_NODES+1]
    const float* __restrict__ scalar_p,  // &scalars[l]
    const float* __restrict__ W,         // [64,64] (row j = output feature), or null
    const float* __restrict__ bvec,      // [64], or null
    float*       __restrict__ h_out)     // [N_NODES, 64]
{
    __shared__ float Wlds[64 * 65];      // padded to avoid stride-64 bank conflicts

    const int lane = threadIdx.x & 63;
    const int wave = threadIdx.x >> 6;

    if (FUSE) {
        for (int i = threadIdx.x; i < 64 * 64; i += 256) {
            int j = i >> 6, d = i & 63;
            Wlds[j * 65 + d] = W[i];
        }
        __syncthreads();
    }

    const int row = blockIdx.x * 4 + wave;
    if (row >= N_NODES) return;

    const float s = scalar_p[0];
    const int e0 = row_ptr[row];
    const int e1 = row_ptr[row + 1];

    float acc = 0.f;
    for (int e = e0; e < e1; ++e) {
        // cols[e], vals[e] are wave-uniform -> scalar loads
        int   c = cols[e];
        float v = vals[e];
        acc = fmaf(v, h_in[c * D_FEAT + lane], acc);  // coalesced 256B gather
    }
    acc *= s;
    // ELU (alpha=1)
    acc = acc > 0.f ? acc : expm1f(acc);

    if (!FUSE) {
        h_out[row * D_FEAT + lane] = acc;
    } else {
        float o = bvec[lane];
        #pragma unroll
        for (int d = 0; d < D_FEAT; ++d) {
            float hd = __shfl(acc, d, 64);
            o = fmaf(hd, Wlds[lane * 65 + d], o);
        }
        h_out[row * D_FEAT + lane] = o;
    }
}

extern "C" void kernel_launch(void* const* d_in, const int* in_sizes, int n_in,
                              void* d_out, int out_size, void* d_ws, size_t ws_size,
                              hipStream_t stream) {
    const float* x       = (const float*)d_in[0];
    const int*   rows    = (const int*)  d_in[1];
    const int*   cols    = (const int*)  d_in[2];
    const float* vals    = (const float*)d_in[3];
    const float* scalars = (const float*)d_in[4];
    const float* W       = (const float*)d_in[5];
    const float* b       = (const float*)d_in[6];
    float* out = (float*)d_out;

    // ws layout: row_ptr [N_NODES+1] ints, then h1 [N_NODES*64] floats
    int*   row_ptr = (int*)d_ws;
    float* h1 = (float*)((char*)d_ws + ((sizeof(int) * (N_NODES + 1) + 255) & ~size_t(255)));

    build_row_ptr<<<(N_NODES + 1 + 255) / 256, 256, 0, stream>>>(rows, row_ptr);

    const int nblocks = (N_NODES + 3) / 4;
    // Layer 0: x -> h1
    gcn_layer<false><<<nblocks, 256, 0, stream>>>(x, cols, vals, row_ptr,
                                                  scalars + 0, nullptr, nullptr, h1);
    // Layer 1 fused with final projection: h1 -> out
    gcn_layer<true><<<nblocks, 256, 0, stream>>>(h1, cols, vals, row_ptr,
                                                 scalars + 1, W, b, out);
}

// Round 2
// 88.275 us; speedup vs baseline: 2.1593x; 2.1593x over previous
//
#include <hip/hip_runtime.h>
#include <math.h>

#define N_NODES 50000
#define N_EDGES 800000
#define D_FEAT 64

// Kernel 1: row_ptr[r] = lower_bound(rows, r) for r in [0, N_NODES]
__global__ __launch_bounds__(256) void build_row_ptr(const int* __restrict__ rows,
                                                     int* __restrict__ row_ptr) {
    int r = blockIdx.x * blockDim.x + threadIdx.x;
    if (r > N_NODES) return;
    int lo = 0, hi = N_EDGES;
    while (lo < hi) {
        int mid = (lo + hi) >> 1;
        if (rows[mid] < r) lo = mid + 1; else hi = mid;
    }
    row_ptr[r] = lo;
}

// Kernel 2: one wave per row. 16 lanes per edge (float4 of features),
// 4 edge-groups per wave, unrolled x2 -> 8 independent gathers in flight.
// y[row][f] = elu(scalar * sum_e vals[e] * h_in[cols[e]][f])
// If FUSE: out[row][j] = b[j] + sum_d y[row][d] * W[j][d]
template <bool FUSE>
__global__ __launch_bounds__(256) void gcn_layer(
    const float* __restrict__ h_in,      // [N_NODES, 64]
    const int*   __restrict__ cols,      // [N_EDGES]
    const float* __restrict__ vals,      // [N_EDGES]
    const int*   __restrict__ row_ptr,   // [N_NODES+1]
    const float* __restrict__ scalar_p,  // &scalars[l]
    const float* __restrict__ W,         // [64,64] row j = output feature (or null)
    const float* __restrict__ bvec,      // [64] (or null)
    float*       __restrict__ h_out)     // [N_NODES, 64]
{
    __shared__ float Wlds[FUSE ? 64 * 65 : 1];  // padded: bank = (j+d)%32, conflict-free
    __shared__ float ylds[FUSE ? 4 * 64 : 1];   // one 64-float row per wave

    const int lane = threadIdx.x & 63;
    const int wave = threadIdx.x >> 6;
    const int g    = lane >> 4;   // edge subgroup 0..3
    const int f4   = lane & 15;   // float4 index within the 64-feature row

    if constexpr (FUSE) {
        for (int i = threadIdx.x; i < 64 * 64; i += 256) {
            Wlds[(i >> 6) * 65 + (i & 63)] = W[i];
        }
        __syncthreads();
    }

    const int row = blockIdx.x * 4 + wave;
    if (row >= N_NODES) return;

    const float s = scalar_p[0];
    const int e0 = row_ptr[row];
    const int e1 = row_ptr[row + 1];

    float ax = 0.f, ay = 0.f, az = 0.f, aw = 0.f;
    float bx = 0.f, by = 0.f, bz = 0.f, bw = 0.f;

    for (int e = e0; e < e1; e += 8) {
        const int eA = e + g;
        const int eB = e + 4 + g;
        const int iA = eA < e1 ? eA : e1 - 1;   // clamp keeps loads in-bounds
        const int iB = eB < e1 ? eB : e1 - 1;
        const int cA = cols[iA];
        const int cB = cols[iB];
        float vA = vals[iA]; vA = (eA < e1) ? vA : 0.f;
        float vB = vals[iB]; vB = (eB < e1) ? vB : 0.f;
        const float4 gA = *reinterpret_cast<const float4*>(h_in + (size_t)cA * D_FEAT + f4 * 4);
        const float4 gB = *reinterpret_cast<const float4*>(h_in + (size_t)cB * D_FEAT + f4 * 4);
        ax = fmaf(vA, gA.x, ax); ay = fmaf(vA, gA.y, ay);
        az = fmaf(vA, gA.z, az); aw = fmaf(vA, gA.w, aw);
        bx = fmaf(vB, gB.x, bx); by = fmaf(vB, gB.y, by);
        bz = fmaf(vB, gB.z, bz); bw = fmaf(vB, gB.w, bw);
    }
    ax += bx; ay += by; az += bz; aw += bw;

    // Reduce across the 4 edge-groups (butterfly): all lanes end with full sums.
    ax += __shfl_xor(ax, 16, 64); ay += __shfl_xor(ay, 16, 64);
    az += __shfl_xor(az, 16, 64); aw += __shfl_xor(aw, 16, 64);
    ax += __shfl_xor(ax, 32, 64); ay += __shfl_xor(ay, 32, 64);
    az += __shfl_xor(az, 32, 64); aw += __shfl_xor(aw, 32, 64);

    ax *= s; ay *= s; az *= s; aw *= s;
    ax = ax > 0.f ? ax : expm1f(ax);
    ay = ay > 0.f ? ay : expm1f(ay);
    az = az > 0.f ? az : expm1f(az);
    aw = aw > 0.f ? aw : expm1f(aw);

    if constexpr (!FUSE) {
        if (g == 0) {
            float4 r; r.x = ax; r.y = ay; r.z = az; r.w = aw;
            *reinterpret_cast<float4*>(h_out + (size_t)row * D_FEAT + f4 * 4) = r;
        }
    } else {
        float* yrow = ylds + wave * 64;
        if (g == 0) {
            float4 r; r.x = ax; r.y = ay; r.z = az; r.w = aw;
            *reinterpret_cast<float4*>(yrow + f4 * 4) = r;
        }
        // same-wave ds_write -> ds_read ordering
        asm volatile("s_waitcnt lgkmcnt(0)" ::: "memory");
        const int j = lane;
        float o = bvec[j];
        #pragma unroll
        for (int d0 = 0; d0 < 16; ++d0) {
            const float4 y4 = *reinterpret_cast<const float4*>(yrow + d0 * 4);  // uniform -> broadcast
            const float* wr = Wlds + j * 65 + d0 * 4;
            o = fmaf(y4.x, wr[0], o);
            o = fmaf(y4.y, wr[1], o);
            o = fmaf(y4.z, wr[2], o);
            o = fmaf(y4.w, wr[3], o);
        }
        h_out[(size_t)row * D_FEAT + j] = o;
    }
}

extern "C" void kernel_launch(void* const* d_in, const int* in_sizes, int n_in,
                              void* d_out, int out_size, void* d_ws, size_t ws_size,
                              hipStream_t stream) {
    const float* x       = (const float*)d_in[0];
    const int*   rows    = (const int*)  d_in[1];
    const int*   cols    = (const int*)  d_in[2];
    const float* vals    = (const float*)d_in[3];
    const float* scalars = (const float*)d_in[4];
    const float* W       = (const float*)d_in[5];
    const float* b       = (const float*)d_in[6];
    float* out = (float*)d_out;

    // ws layout: row_ptr [N_NODES+1] ints, then h1 [N_NODES*64] floats
    int*   row_ptr = (int*)d_ws;
    float* h1 = (float*)((char*)d_ws + ((sizeof(int) * (N_NODES + 1) + 255) & ~size_t(255)));

    build_row_ptr<<<(N_NODES + 1 + 255) / 256, 256, 0, stream>>>(rows, row_ptr);

    const int nblocks = (N_NODES + 3) / 4;
    // Layer 0: x -> h1
    gcn_layer<false><<<nblocks, 256, 0, stream>>>(x, cols, vals, row_ptr,
                                                  scalars + 0, nullptr, nullptr, h1);
    // Layer 1 fused with final projection: h1 -> out
    gcn_layer<true><<<nblocks, 256, 0, stream>>>(h1, cols, vals, row_ptr,
                                                 scalars + 1, W, b, out);
}

// Round 3
// 81.876 us; speedup vs baseline: 2.3280x; 1.0782x over previous
//
#include <hip/hip_runtime.h>
#include <math.h>

#define N_NODES 50000
#define N_EDGES 800000
#define D_FEAT 64

// Kernel 1: row_ptr[r] = lower_bound(rows, r) for r in [0, N_NODES]
__global__ __launch_bounds__(256) void build_row_ptr(const int* __restrict__ rows,
                                                     int* __restrict__ row_ptr) {
    int r = blockIdx.x * blockDim.x + threadIdx.x;
    if (r > N_NODES) return;
    int lo = 0, hi = N_EDGES;
    while (lo < hi) {
        int mid = (lo + hi) >> 1;
        if (rows[mid] < r) lo = mid + 1; else hi = mid;
    }
    row_ptr[r] = lo;
}

// Fast ELU: native v_exp_f32 path. Absolute-error threshold is 0.765; native
// exp is ~1 ulp so exp(x)-1 is more than accurate enough (expm1 only matters
// for RELATIVE error near 0).
__device__ __forceinline__ float elu_f(float x) {
    return x > 0.f ? x : (__expf(x) - 1.f);
}

// Kernel 2: one wave per row. 16 lanes per edge (float4 of features),
// 4 edge-groups per wave, bulk iterations cover 16 edges (4 independent
// float4 gathers in flight, no clamping); one masked tail iteration.
// If FUSE: out[row][j] = b[j] + sum_d y[row][d] * W[j][d]
template <bool FUSE>
__global__ __launch_bounds__(256) void gcn_layer(
    const float* __restrict__ h_in,      // [N_NODES, 64]
    const int*   __restrict__ cols,      // [N_EDGES]
    const float* __restrict__ vals,      // [N_EDGES]
    const int*   __restrict__ row_ptr,   // [N_NODES+1]
    const float* __restrict__ scalar_p,  // &scalars[l]
    const float* __restrict__ W,         // [64,64] row j = output feature (or null)
    const float* __restrict__ bvec,      // [64] (or null)
    float*       __restrict__ h_out)     // [N_NODES, 64]
{
    __shared__ float Wlds[FUSE ? 64 * 65 : 1];  // padded: conflict-free per-lane reads
    __shared__ float ylds[FUSE ? 4 * 64 : 1];   // one 64-float y row per wave

    const int lane = threadIdx.x & 63;
    const int wave = threadIdx.x >> 6;
    const int g    = lane >> 4;   // edge subgroup 0..3
    const int f4   = lane & 15;   // float4 index within the 64-feature row

    if constexpr (FUSE) {
        for (int i = threadIdx.x; i < 64 * 64; i += 256)
            Wlds[(i >> 6) * 65 + (i & 63)] = W[i];
        __syncthreads();
    }

    const int row = blockIdx.x * 4 + wave;
    if (row >= N_NODES) return;

    const float s  = scalar_p[0];
    const int  e0  = row_ptr[row];
    const int  e1  = row_ptr[row + 1];

    const float4* __restrict__ h4 = reinterpret_cast<const float4*>(h_in);

    float4 a0 = make_float4(0.f, 0.f, 0.f, 0.f);
    float4 a1 = a0, a2 = a0, a3 = a0;

    int e = e0;
    // Bulk: 16 edges per iteration, no clamping, 4 gathers in flight.
    for (; e + 16 <= e1; e += 16) {
        const int i0 = e + g, i1 = e + 4 + g, i2 = e + 8 + g, i3 = e + 12 + g;
        const int c0 = cols[i0], c1 = cols[i1], c2 = cols[i2], c3 = cols[i3];
        const float v0 = vals[i0], v1 = vals[i1], v2 = vals[i2], v3 = vals[i3];
        const float4 g0 = h4[c0 * 16 + f4];
        const float4 g1 = h4[c1 * 16 + f4];
        const float4 g2 = h4[c2 * 16 + f4];
        const float4 g3 = h4[c3 * 16 + f4];
        a0.x = fmaf(v0, g0.x, a0.x); a0.y = fmaf(v0, g0.y, a0.y);
        a0.z = fmaf(v0, g0.z, a0.z); a0.w = fmaf(v0, g0.w, a0.w);
        a1.x = fmaf(v1, g1.x, a1.x); a1.y = fmaf(v1, g1.y, a1.y);
        a1.z = fmaf(v1, g1.z, a1.z); a1.w = fmaf(v1, g1.w, a1.w);
        a2.x = fmaf(v2, g2.x, a2.x); a2.y = fmaf(v2, g2.y, a2.y);
        a2.z = fmaf(v2, g2.z, a2.z); a2.w = fmaf(v2, g2.w, a2.w);
        a3.x = fmaf(v3, g3.x, a3.x); a3.y = fmaf(v3, g3.y, a3.y);
        a3.z = fmaf(v3, g3.z, a3.z); a3.w = fmaf(v3, g3.w, a3.w);
    }
    // Tail: one masked 16-edge iteration (loads clamped in-bounds, vals zeroed).
    if (e < e1) {
        const int em = e1 - 1;
        const int t0 = e + g, t1 = e + 4 + g, t2 = e + 8 + g, t3 = e + 12 + g;
        const int i0 = t0 < em ? t0 : em;
        const int i1 = t1 < em ? t1 : em;
        const int i2 = t2 < em ? t2 : em;
        const int i3 = t3 < em ? t3 : em;
        const int c0 = cols[i0], c1 = cols[i1], c2 = cols[i2], c3 = cols[i3];
        float v0 = vals[i0], v1 = vals[i1], v2 = vals[i2], v3 = vals[i3];
        v0 = (t0 < e1) ? v0 : 0.f;
        v1 = (t1 < e1) ? v1 : 0.f;
        v2 = (t2 < e1) ? v2 : 0.f;
        v3 = (t3 < e1) ? v3 : 0.f;
        const float4 g0 = h4[c0 * 16 + f4];
        const float4 g1 = h4[c1 * 16 + f4];
        const float4 g2 = h4[c2 * 16 + f4];
        const float4 g3 = h4[c3 * 16 + f4];
        a0.x = fmaf(v0, g0.x, a0.x); a0.y = fmaf(v0, g0.y, a0.y);
        a0.z = fmaf(v0, g0.z, a0.z); a0.w = fmaf(v0, g0.w, a0.w);
        a1.x = fmaf(v1, g1.x, a1.x); a1.y = fmaf(v1, g1.y, a1.y);
        a1.z = fmaf(v1, g1.z, a1.z); a1.w = fmaf(v1, g1.w, a1.w);
        a2.x = fmaf(v2, g2.x, a2.x); a2.y = fmaf(v2, g2.y, a2.y);
        a2.z = fmaf(v2, g2.z, a2.z); a2.w = fmaf(v2, g2.w, a2.w);
        a3.x = fmaf(v3, g3.x, a3.x); a3.y = fmaf(v3, g3.y, a3.y);
        a3.z = fmaf(v3, g3.z, a3.z); a3.w = fmaf(v3, g3.w, a3.w);
    }

    // Combine the 4 accumulator sets, then reduce across edge-groups.
    float ax = (a0.x + a1.x) + (a2.x + a3.x);
    float ay = (a0.y + a1.y) + (a2.y + a3.y);
    float az = (a0.z + a1.z) + (a2.z + a3.z);
    float aw = (a0.w + a1.w) + (a2.w + a3.w);

    ax += __shfl_xor(ax, 16, 64); ay += __shfl_xor(ay, 16, 64);
    az += __shfl_xor(az, 16, 64); aw += __shfl_xor(aw, 16, 64);
    ax += __shfl_xor(ax, 32, 64); ay += __shfl_xor(ay, 32, 64);
    az += __shfl_xor(az, 32, 64); aw += __shfl_xor(aw, 32, 64);

    ax = elu_f(ax * s);
    ay = elu_f(ay * s);
    az = elu_f(az * s);
    aw = elu_f(aw * s);

    if constexpr (!FUSE) {
        if (g == 0) {
            float4 r; r.x = ax; r.y = ay; r.z = az; r.w = aw;
            *reinterpret_cast<float4*>(h_out + (size_t)row * D_FEAT + f4 * 4) = r;
        }
    } else {
        float* yrow = ylds + wave * 64;
        if (g == 0) {
            float4 r; r.x = ax; r.y = ay; r.z = az; r.w = aw;
            *reinterpret_cast<float4*>(yrow + f4 * 4) = r;
        }
        // same-wave ds_write -> ds_read ordering
        asm volatile("s_waitcnt lgkmcnt(0)" ::: "memory");
        const int j = lane;
        float o = bvec[j];
        #pragma unroll
        for (int d0 = 0; d0 < 16; ++d0) {
            const float4 y4 = *reinterpret_cast<const float4*>(yrow + d0 * 4);  // uniform -> broadcast
            const float* wr = Wlds + j * 65 + d0 * 4;
            o = fmaf(y4.x, wr[0], o);
            o = fmaf(y4.y, wr[1], o);
            o = fmaf(y4.z, wr[2], o);
            o = fmaf(y4.w, wr[3], o);
        }
        h_out[(size_t)row * D_FEAT + j] = o;
    }
}

extern "C" void kernel_launch(void* const* d_in, const int* in_sizes, int n_in,
                              void* d_out, int out_size, void* d_ws, size_t ws_size,
                              hipStream_t stream) {
    const float* x       = (const float*)d_in[0];
    const int*   rows    = (const int*)  d_in[1];
    const int*   cols    = (const int*)  d_in[2];
    const float* vals    = (const float*)d_in[3];
    const float* scalars = (const float*)d_in[4];
    const float* W       = (const float*)d_in[5];
    const float* b       = (const float*)d_in[6];
    float* out = (float*)d_out;

    // ws layout: row_ptr [N_NODES+1] ints, then h1 [N_NODES*64] floats
    int*   row_ptr = (int*)d_ws;
    float* h1 = (float*)((char*)d_ws + ((sizeof(int) * (N_NODES + 1) + 255) & ~size_t(255)));

    build_row_ptr<<<(N_NODES + 1 + 255) / 256, 256, 0, stream>>>(rows, row_ptr);

    const int nblocks = (N_NODES + 3) / 4;
    // Layer 0: x -> h1
    gcn_layer<false><<<nblocks, 256, 0, stream>>>(x, cols, vals, row_ptr,
                                                  scalars + 0, nullptr, nullptr, h1);
    // Layer 1 fused with final projection: h1 -> out
    gcn_layer<true><<<nblocks, 256, 0, stream>>>(h1, cols, vals, row_ptr,
                                                 scalars + 1, W, b, out);
}

// Round 4
// 71.717 us; speedup vs baseline: 2.6578x; 1.1417x over previous
//
#include <hip/hip_runtime.h>
#include <math.h>

#define N_NODES 50000
#define N_EDGES 800000
#define D_FEAT 64
#define NBLK 3125   // 16 rows per block * 3125 = 50000 exactly

// Prep: row_ptr[r] = lower_bound(rows, r); optionally pack edges as
// (col*256 byte-offset, val bits) int2 for single-load edge streaming.
__global__ __launch_bounds__(256) void prep_kernel(const int* __restrict__ rows,
                                                   const int* __restrict__ cols,
                                                   const float* __restrict__ vals,
                                                   int* __restrict__ row_ptr,
                                                   int2* __restrict__ pairs,
                                                   int do_pack) {
    int i = blockIdx.x * blockDim.x + threadIdx.x;
    if (i <= N_NODES) {
        int lo = 0, hi = N_EDGES;
        while (lo < hi) {
            int mid = (lo + hi) >> 1;
            if (rows[mid] < i) lo = mid + 1; else hi = mid;
        }
        row_ptr[i] = lo;
    }
    if (do_pack && i < N_EDGES) {
        pairs[i] = make_int2(cols[i] << 8, __float_as_int(vals[i]));
    }
}

// Fast ELU: native v_exp_f32 (abs threshold 0.765 makes expm1 precision moot).
__device__ __forceinline__ float elu_f(float x) {
    return x > 0.f ? x : (__expf(x) - 1.f);
}

// One 8-edge step for one row-group. Fully unrolled -> all arrays in registers.
template <bool PACKED, bool MASKED>
__device__ __forceinline__ void edge_step8(const char* __restrict__ hb,
                                           const int2* __restrict__ pairs,
                                           const int* __restrict__ cols,
                                           const float* __restrict__ vals,
                                           int e, int e1, int f16,
                                           float4& A, float4& B) {
    int off[8]; float v[8];
    #pragma unroll
    for (int k = 0; k < 8; ++k) {
        const int t = e + k;
        const int idx = MASKED ? (t < e1 ? t : e1 - 1) : t;
        if constexpr (PACKED) {
            const int2 p = pairs[idx];
            off[k] = p.x;
            v[k] = __int_as_float(p.y);
        } else {
            off[k] = cols[idx] << 8;
            v[k] = vals[idx];
        }
        if (MASKED) v[k] = (t < e1) ? v[k] : 0.f;
    }
    float4 gg[8];
    #pragma unroll
    for (int k = 0; k < 8; ++k)
        gg[k] = *reinterpret_cast<const float4*>(hb + (unsigned)(off[k] + f16));
    #pragma unroll
    for (int k = 0; k < 8; ++k) {
        float4& acc = (k & 1) ? B : A;
        acc.x = fmaf(v[k], gg[k].x, acc.x);
        acc.y = fmaf(v[k], gg[k].y, acc.y);
        acc.z = fmaf(v[k], gg[k].z, acc.z);
        acc.w = fmaf(v[k], gg[k].w, acc.w);
    }
}

// SpMM layer: 4 waves/block, 4 row-groups/wave (16 lanes per row, float4 of
// features per lane). No cross-group reduce. Up to 32 gathers in flight/wave.
// If FUSE: out[row][j] = b[j] + sum_d y[row][d] * W[j][d] per wave (4 rows).
template <bool FUSE, bool PACKED>
__global__ __launch_bounds__(256) void gcn_layer(
    const float* __restrict__ h_in,      // [N_NODES, 64]
    const int2*  __restrict__ pairs,     // packed edges (or null)
    const int*   __restrict__ cols,      // fallback
    const float* __restrict__ vals,      // fallback
    const int*   __restrict__ row_ptr,   // [N_NODES+1]
    const float* __restrict__ scalar_p,  // &scalars[l]
    const float* __restrict__ W,         // [64,64] (or null)
    const float* __restrict__ bvec,      // [64] (or null)
    float*       __restrict__ h_out)     // [N_NODES, 64]
{
    __shared__ float Wlds[FUSE ? 64 * 65 : 1];   // stride 65: 2-way (free) reads
    __shared__ float ylds[FUSE ? 4 * 4 * 68 : 1];// [wave][row][68 pad]

    const int lane = threadIdx.x & 63;
    const int wave = threadIdx.x >> 6;
    const int g    = lane >> 4;          // row-group 0..3
    const int f4   = lane & 15;          // float4 index in feature row
    const int f16  = f4 * 16;            // byte offset of this lane's chunk

    if constexpr (FUSE) {
        for (int i = threadIdx.x; i < 64 * 64; i += 256)
            Wlds[(i >> 6) * 65 + (i & 63)] = W[i];
        __syncthreads();
    }

    const int row = blockIdx.x * 16 + wave * 4 + g;
    const float s  = scalar_p[0];
    const int  e0  = row_ptr[row];
    const int  e1  = row_ptr[row + 1];
    const char* hb = (const char*)h_in;

    float4 A = make_float4(0.f, 0.f, 0.f, 0.f);
    float4 B = A;

    int e = e0;
    for (; e + 8 <= e1; e += 8)
        edge_step8<PACKED, false>(hb, pairs, cols, vals, e, e1, f16, A, B);
    if (e < e1)
        edge_step8<PACKED, true>(hb, pairs, cols, vals, e, e1, f16, A, B);

    float4 acc;
    acc.x = elu_f((A.x + B.x) * s);
    acc.y = elu_f((A.y + B.y) * s);
    acc.z = elu_f((A.z + B.z) * s);
    acc.w = elu_f((A.w + B.w) * s);

    if constexpr (!FUSE) {
        *reinterpret_cast<float4*>(h_out + (size_t)row * D_FEAT + f16 / 4) = acc;
    } else {
        float* yw = ylds + wave * (4 * 68);
        *reinterpret_cast<float4*>(yw + g * 68 + f4 * 4) = acc;
        asm volatile("s_waitcnt lgkmcnt(0)" ::: "memory");  // same-wave ds ordering

        const int j = lane;
        const float bj = bvec[j];
        float o0 = bj, o1 = bj, o2 = bj, o3 = bj;
        #pragma unroll
        for (int d0 = 0; d0 < 16; ++d0) {
            const float* wr = Wlds + j * 65 + d0 * 4;  // 2-way banked: free
            const float w0 = wr[0], w1 = wr[1], w2 = wr[2], w3 = wr[3];
            const float4 y0 = *reinterpret_cast<const float4*>(yw + 0 * 68 + d0 * 4);
            const float4 y1 = *reinterpret_cast<const float4*>(yw + 1 * 68 + d0 * 4);
            const float4 y2 = *reinterpret_cast<const float4*>(yw + 2 * 68 + d0 * 4);
            const float4 y3 = *reinterpret_cast<const float4*>(yw + 3 * 68 + d0 * 4);
            o0 = fmaf(y0.x, w0, o0); o0 = fmaf(y0.y, w1, o0);
            o0 = fmaf(y0.z, w2, o0); o0 = fmaf(y0.w, w3, o0);
            o1 = fmaf(y1.x, w0, o1); o1 = fmaf(y1.y, w1, o1);
            o1 = fmaf(y1.z, w2, o1); o1 = fmaf(y1.w, w3, o1);
            o2 = fmaf(y2.x, w0, o2); o2 = fmaf(y2.y, w1, o2);
            o2 = fmaf(y2.z, w2, o2); o2 = fmaf(y2.w, w3, o2);
            o3 = fmaf(y3.x, w0, o3); o3 = fmaf(y3.y, w1, o3);
            o3 = fmaf(y3.z, w2, o3); o3 = fmaf(y3.w, w3, o3);
        }
        const size_t rbase = (size_t)(blockIdx.x * 16 + wave * 4) * D_FEAT;
        h_out[rbase + 0 * D_FEAT + j] = o0;
        h_out[rbase + 1 * D_FEAT + j] = o1;
        h_out[rbase + 2 * D_FEAT + j] = o2;
        h_out[rbase + 3 * D_FEAT + j] = o3;
    }
}

extern "C" void kernel_launch(void* const* d_in, const int* in_sizes, int n_in,
                              void* d_out, int out_size, void* d_ws, size_t ws_size,
                              hipStream_t stream) {
    const float* x       = (const float*)d_in[0];
    const int*   rows    = (const int*)  d_in[1];
    const int*   cols    = (const int*)  d_in[2];
    const float* vals    = (const float*)d_in[3];
    const float* scalars = (const float*)d_in[4];
    const float* W       = (const float*)d_in[5];
    const float* b       = (const float*)d_in[6];
    float* out = (float*)d_out;

    // ws layout: row_ptr | h1 | (optional) packed edge pairs
    const size_t rp_b  = (sizeof(int) * (N_NODES + 1) + 255) & ~size_t(255);
    const size_t h1_b  = (sizeof(float) * (size_t)N_NODES * D_FEAT + 255) & ~size_t(255);
    const size_t pr_b  = sizeof(int2) * (size_t)N_EDGES;
    int*   row_ptr = (int*)d_ws;
    float* h1      = (float*)((char*)d_ws + rp_b);
    const bool packed = ws_size >= rp_b + h1_b + pr_b;
    int2*  pairs   = packed ? (int2*)((char*)d_ws + rp_b + h1_b) : nullptr;

    prep_kernel<<<(N_EDGES + 255) / 256, 256, 0, stream>>>(rows, cols, vals,
                                                           row_ptr, pairs,
                                                           packed ? 1 : 0);

    if (packed) {
        gcn_layer<false, true><<<NBLK, 256, 0, stream>>>(x, pairs, cols, vals, row_ptr,
                                                         scalars + 0, nullptr, nullptr, h1);
        gcn_layer<true, true><<<NBLK, 256, 0, stream>>>(h1, pairs, cols, vals, row_ptr,
                                                        scalars + 1, W, b, out);
    } else {
        gcn_layer<false, false><<<NBLK, 256, 0, stream>>>(x, nullptr, cols, vals, row_ptr,
                                                          scalars + 0, nullptr, nullptr, h1);
        gcn_layer<true, false><<<NBLK, 256, 0, stream>>>(h1, nullptr, cols, vals, row_ptr,
                                                         scalars + 1, W, b, out);
    }
}